// Round 17
// baseline (155.857 us; speedup 1.0000x reference)
//
#include <hip/hip_runtime.h>
#include <math.h>
#include <stdint.h>

typedef __attribute__((ext_vector_type(8))) short short8;
typedef __attribute__((ext_vector_type(4))) float f32x4;

__device__ __forceinline__ uint32_t cvt_pk_bf16(float lo, float hi) {
  uint32_t r;
  asm("v_cvt_pk_bf16_f32 %0, %1, %2" : "=v"(r) : "v"(lo), "v"(hi));
  return r;
}

// inverse-distance weight; invalid j has cx=cy=1e30 -> d2 overflows to inf
// -> rcp(inf)=0, so invalid columns contribute exactly 0.
__device__ __forceinline__ float wfun(float hx, float hy, float cx, float cy) {
  float dx = hx - cx, dy = hy - cy;
  float d = __builtin_amdgcn_sqrtf(fmaf(dx, dx, dy * dy));
  return __builtin_amdgcn_rcpf(d + 1e-4f);
}

// ---------------------------------------------------------------------------
// Kernel 1: hp = tanh(batch@W_h + b_h); hx,hy,validf,cxy per row. (verified)
__global__ __launch_bounds__(256) void k_head(
    const float* __restrict__ batch, const float* __restrict__ xywh,
    const float* __restrict__ W_h, const float* __restrict__ b_h,
    float* __restrict__ hp_out, float* __restrict__ hx, float* __restrict__ hy,
    float* __restrict__ validf, float2* __restrict__ cxy, int S, int F) {
  int wid = threadIdx.x >> 6;
  int lane = threadIdx.x & 63;
  int row = blockIdx.x * 4 + wid;
  if (row >= S) return;
  const float4* brow = (const float4*)(batch + (size_t)row * F);
  const float4* wh4 = (const float4*)W_h;  // W_h is [F,2] row-major
  int nf4 = F >> 2;
  float acc0 = 0.f, acc1 = 0.f;
  for (int k4 = lane; k4 < nf4; k4 += 64) {
    float4 b = brow[k4];
    float4 wa = wh4[2 * k4];
    float4 wb = wh4[2 * k4 + 1];
    acc0 += b.x * wa.x + b.y * wa.z + b.z * wb.x + b.w * wb.z;
    acc1 += b.x * wa.y + b.y * wa.w + b.z * wb.y + b.w * wb.w;
  }
  #pragma unroll
  for (int off = 32; off; off >>= 1) {
    acc0 += __shfl_xor(acc0, off, 64);
    acc1 += __shfl_xor(acc1, off, 64);
  }
  if (lane == 0) {
    float hp0 = tanhf(acc0 + b_h[0]);
    float hp1 = tanhf(acc1 + b_h[1]);
    float4 xy = ((const float4*)xywh)[row];
    hp_out[2 * row] = hp0;
    hp_out[2 * row + 1] = hp1;
    hx[row] = hp0 * xy.z * 4.0f + xy.x;  // SIGMA_X = 4
    hy[row] = hp1 * xy.w * 1.0f + xy.y;  // SIGMA_Y = 1
    bool v = (xy.x + xy.y + xy.z + xy.w >= 1e-8f);
    validf[row] = v ? 1.0f : 0.0f;
    cxy[row] = v ? make_float2(xy.x, xy.y) : make_float2(1e30f, 1e30f);
  }
}

// ---------------------------------------------------------------------------
// Kernel 1b: WgT[a][k] = bf16(Wg[k][a])  (verified)
__global__ __launch_bounds__(256) void k_prep_w(
    const float* __restrict__ Wg, uint16_t* __restrict__ WgT, int F, int A) {
  int idx = blockIdx.x * 256 + threadIdx.x;
  int a = idx % A;
  int k0 = (idx / A) * 8;
  if (k0 >= F) return;
  float f[8];
  #pragma unroll
  for (int e = 0; e < 8; ++e) f[e] = Wg[(size_t)(k0 + e) * A + a];
  uint4 v;
  v.x = cvt_pk_bf16(f[0], f[1]);
  v.y = cvt_pk_bf16(f[2], f[3]);
  v.z = cvt_pk_bf16(f[4], f[5]);
  v.w = cvt_pk_bf16(f[6], f[7]);
  *(uint4*)(WgT + (size_t)a * F + k0) = v;
}

// ---------------------------------------------------------------------------
// Kernel 2: targets via bf16 MFMA; tiled output tgt2[jb][a][jj]. Verified
// body; occupancy fix: each block now covers 128 cols (grid (A/128, S/32) =
// 512 blocks -> 2 blocks/CU -> 2 waves/SIMD, was 1).
__global__ __launch_bounds__(256) void k_targets_mfma(
    const float* __restrict__ batch, const uint16_t* __restrict__ WgT,
    const float* __restrict__ bg, uint16_t* __restrict__ tgt2,
    int S, int F, int A) {
  int t = threadIdx.x;
  int lane = t & 63, wid = t >> 6;
  int wm = wid >> 1, wn = wid & 1;
  int i0 = blockIdx.y * 32;
  int row = i0 + wm * 16 + (lane & 15);
  int kch = lane >> 4;
  const float* ab = batch + (size_t)row * F + kch * 8;
  int ncol0 = blockIdx.x * 128 + wn * 64 + (lane & 15);
  const uint16_t* bb = WgT + (size_t)ncol0 * F + kch * 8;

  f32x4 acc[4] = {};
  float4 a0 = *(const float4*)(ab);
  float4 a1 = *(const float4*)(ab + 4);
  short8 bf[4];
  #pragma unroll
  for (int nf = 0; nf < 4; ++nf)
    bf[nf] = *(const short8*)(bb + (size_t)nf * 16 * F);

  for (int k0 = 0; k0 < F; k0 += 32) {
    int kn = (k0 + 32 < F) ? k0 + 32 : 0;  // wrap prefetch (harmless)
    float4 na0 = *(const float4*)(ab + kn);
    float4 na1 = *(const float4*)(ab + kn + 4);
    short8 nbf[4];
    #pragma unroll
    for (int nf = 0; nf < 4; ++nf)
      nbf[nf] = *(const short8*)(bb + kn + (size_t)nf * 16 * F);
    union { short8 s; uint32_t u[4]; } af;
    af.u[0] = cvt_pk_bf16(a0.x, a0.y);
    af.u[1] = cvt_pk_bf16(a0.z, a0.w);
    af.u[2] = cvt_pk_bf16(a1.x, a1.y);
    af.u[3] = cvt_pk_bf16(a1.z, a1.w);
    #pragma unroll
    for (int nf = 0; nf < 4; ++nf)
      acc[nf] = __builtin_amdgcn_mfma_f32_16x16x32_bf16(af.s, bf[nf], acc[nf], 0, 0, 0);
    a0 = na0; a1 = na1;
    #pragma unroll
    for (int nf = 0; nf < 4; ++nf) bf[nf] = nbf[nf];
  }

  int jb = blockIdx.y;
  int rloc = wm * 16 + (lane >> 4) * 4;   // row within tile, mult of 4
  #pragma unroll
  for (int nf = 0; nf < 4; ++nf) {
    int col = ncol0 + nf * 16;
    float b = bg[col];
    float o0 = fmaxf(acc[nf][0] + b, 0.f);
    float o1 = fmaxf(acc[nf][1] + b, 0.f);
    float o2 = fmaxf(acc[nf][2] + b, 0.f);
    float o3 = fmaxf(acc[nf][3] + b, 0.f);
    uint2 pk;
    pk.x = cvt_pk_bf16(o0, o1);
    pk.y = cvt_pk_bf16(o2, o3);
    *(uint2*)(tgt2 + ((size_t)jb * A + col) * 32 + rloc) = pk;
  }
}

// ---------------------------------------------------------------------------
// Kernel 3: out = rownorm(W) @ targets.  BM=32 x BN=256, 16 waves =
// 4(kg) x 4(wn). Each wave multiplies its 4 B-frags against BOTH row-group
// A-frags (8 MFMA per 6 LDS reads, was 4 per 5) -> per-j-tile LDS ops
// 56 -> 40. Bt single-buffered [4][256][40] (80 KB), classic 2-barrier step:
// {read+MFMA; issue loads; wfun} bar {write} bar. Af layout as v16-verified.
__global__ __launch_bounds__(1024, 4) void k_gather_v17(
    const uint16_t* __restrict__ tgt2, const float2* __restrict__ cxy,
    const float* __restrict__ hx, const float* __restrict__ hy,
    const float* __restrict__ validf, float* __restrict__ out, int S, int A) {
  __shared__ uint16_t Bt[4][256][40];      // [kg][col][40hw]        80 KB
  __shared__ uint32_t Af[4][2][64][4];     // [kg][rg][lane][slot]    8 KB
  __shared__ float comb[32][260];          // round-robin partial    33.3 KB
  __shared__ float rs_l[4][32][8];         // [kg][row][wjp8]         4 KB
  __shared__ float scale_s[32];

  int t = threadIdx.x;
  int lane = t & 63, wid = t >> 6;
  int kg = wid >> 2;                 // 0..3 (j-quarter)
  int wn = wid & 3;                  // 0..3 (64-col group)
  int i0 = blockIdx.x * 32;
  int kch = lane >> 4;
  int n0 = wn * 64 + (lane & 15);    // col 0..255
  int NT = S / (4 * 32);             // 64 tiles per K-group
  const size_t TSTRIDE = (size_t)A * 32;

  // ---- writer role: (kg wkg, row wr, j-pair-base wjp8) -> 4 wfun/step
  int wkg = t >> 8;
  int v = t & 255;
  int wr = v & 31;                   // 0..31
  int wjp8 = v >> 5;                 // 0..7 -> handles jp = wjp8, wjp8+8
  float hx_w = hx[i0 + wr], hy_w = hy[i0 + wr];
  int rgw = wr >> 4;
  int L0 = (wr & 15) | ((wjp8 >> 2) << 4);
  int L1 = (wr & 15) | (((wjp8 >> 2) + 2) << 4);
  int sl = wjp8 & 3;
  const float2* gCp = cxy + (size_t)wkg * (S >> 2) + 2 * wjp8;

  // ---- staging role: one full 64-B column per thread per step
  int scol = v;                      // 0..255
  const uint16_t* gB0 = tgt2 + (size_t)(wkg * NT) * TSTRIDE + (size_t)scol * 32;

  f32x4 acc0[4] = {};
  f32x4 acc1[4] = {};
  float rs = 0.f;

  // ---- prologue: stage tile 0 (B + w) ; preload c(tile 1)
  {
    uint4 q0 = *(const uint4*)(gB0);
    uint4 q1 = *(const uint4*)(gB0 + 8);
    uint4 q2 = *(const uint4*)(gB0 + 16);
    uint4 q3 = *(const uint4*)(gB0 + 24);
    *(uint4*)&Bt[wkg][scol][0]  = q0;
    *(uint4*)&Bt[wkg][scol][8]  = q1;
    *(uint4*)&Bt[wkg][scol][16] = q2;
    *(uint4*)&Bt[wkg][scol][24] = q3;
    float4 ca = *(const float4*)(gCp);
    float4 cb = *(const float4*)(gCp + 16);
    float wA = wfun(hx_w, hy_w, ca.x, ca.y);
    float wB = wfun(hx_w, hy_w, ca.z, ca.w);
    float wC = wfun(hx_w, hy_w, cb.x, cb.y);
    float wD = wfun(hx_w, hy_w, cb.z, cb.w);
    rs += (wA + wB) + (wC + wD);
    Af[wkg][rgw][L0][sl] = cvt_pk_bf16(wA, wB);
    Af[wkg][rgw][L1][sl] = cvt_pk_bf16(wC, wD);
  }
  __syncthreads();
  float4 ccur0 = *(const float4*)(gCp + 32);
  float4 ccur1 = *(const float4*)(gCp + 48);

  for (int ts = 0; ts < NT; ++ts) {
    int tn = (ts + 1 < NT) ? ts + 1 : 0;
    int tf = (ts + 2 < NT) ? ts + 2 : 0;

    // issue next-tile B loads + c(ts+2)
    const uint16_t* bp = gB0 + (size_t)tn * TSTRIDE;
    uint4 q0 = *(const uint4*)(bp);
    uint4 q1 = *(const uint4*)(bp + 8);
    uint4 q2 = *(const uint4*)(bp + 16);
    uint4 q3 = *(const uint4*)(bp + 24);
    float4 cf0 = *(const float4*)(gCp + (size_t)tf * 32);
    float4 cf1 = *(const float4*)(gCp + (size_t)tf * 32 + 16);

    // read A-frags (both row-groups) + B-frags; 8 MFMA
    short8 a0 = *(const short8*)&Af[kg][0][lane][0];
    short8 a1 = *(const short8*)&Af[kg][1][lane][0];
    const uint16_t* br = &Bt[kg][n0][kch * 8];
    short8 b0 = *(const short8*)(br);
    short8 b1 = *(const short8*)(br + 16 * 40);
    short8 b2 = *(const short8*)(br + 32 * 40);
    short8 b3 = *(const short8*)(br + 48 * 40);

    acc0[0] = __builtin_amdgcn_mfma_f32_16x16x32_bf16(a0, b0, acc0[0], 0, 0, 0);
    acc0[1] = __builtin_amdgcn_mfma_f32_16x16x32_bf16(a0, b1, acc0[1], 0, 0, 0);
    acc0[2] = __builtin_amdgcn_mfma_f32_16x16x32_bf16(a0, b2, acc0[2], 0, 0, 0);
    acc0[3] = __builtin_amdgcn_mfma_f32_16x16x32_bf16(a0, b3, acc0[3], 0, 0, 0);
    acc1[0] = __builtin_amdgcn_mfma_f32_16x16x32_bf16(a1, b0, acc1[0], 0, 0, 0);
    acc1[1] = __builtin_amdgcn_mfma_f32_16x16x32_bf16(a1, b1, acc1[1], 0, 0, 0);
    acc1[2] = __builtin_amdgcn_mfma_f32_16x16x32_bf16(a1, b2, acc1[2], 0, 0, 0);
    acc1[3] = __builtin_amdgcn_mfma_f32_16x16x32_bf16(a1, b3, acc1[3], 0, 0, 0);

    // w-gen for tile ts+1 (rs gated off on the wrapped last step)
    float wA = wfun(hx_w, hy_w, ccur0.x, ccur0.y);
    float wB = wfun(hx_w, hy_w, ccur0.z, ccur0.w);
    float wC = wfun(hx_w, hy_w, ccur1.x, ccur1.y);
    float wD = wfun(hx_w, hy_w, ccur1.z, ccur1.w);
    float g = (ts + 1 < NT) ? 1.f : 0.f;
    rs = fmaf(g, (wA + wB) + (wC + wD), rs);
    uint32_t pkA = cvt_pk_bf16(wA, wB);
    uint32_t pkB = cvt_pk_bf16(wC, wD);

    __syncthreads();   // all reads of tile ts complete

    *(uint4*)&Bt[wkg][scol][0]  = q0;
    *(uint4*)&Bt[wkg][scol][8]  = q1;
    *(uint4*)&Bt[wkg][scol][16] = q2;
    *(uint4*)&Bt[wkg][scol][24] = q3;
    Af[wkg][rgw][L0][sl] = pkA;
    Af[wkg][rgw][L1][sl] = pkB;

    __syncthreads();   // tile ts+1 visible
    ccur0 = cf0;
    ccur1 = cf1;
  }

  // ---- rowsum
  rs_l[wkg][wr][wjp8] = rs;
  __syncthreads();
  if (t < 32) {
    float r = 0.f;
    #pragma unroll
    for (int k = 0; k < 4; ++k)
      #pragma unroll
      for (int jp = 0; jp < 8; ++jp) r += rs_l[k][t][jp];
    float fv = validf[i0 + t];
    scale_s[t] = (fv > 0.f) ? 1.0f / fmaxf(r, 1e-30f) : 0.f;
  }
  __syncthreads();

  // ---- combine kg partials: 3 sequential rounds through one comb buffer
  int rbase = (lane >> 4) * 4;
  #pragma unroll
  for (int round = 1; round < 4; ++round) {
    if (kg == round) {
      #pragma unroll
      for (int r = 0; r < 4; ++r) {
        comb[rbase + r][n0]      = acc0[0][r];
        comb[rbase + r][n0 + 16] = acc0[1][r];
        comb[rbase + r][n0 + 32] = acc0[2][r];
        comb[rbase + r][n0 + 48] = acc0[3][r];
        comb[16 + rbase + r][n0]      = acc1[0][r];
        comb[16 + rbase + r][n0 + 16] = acc1[1][r];
        comb[16 + rbase + r][n0 + 32] = acc1[2][r];
        comb[16 + rbase + r][n0 + 48] = acc1[3][r];
      }
    }
    __syncthreads();
    if (kg == 0) {
      #pragma unroll
      for (int r = 0; r < 4; ++r) {
        acc0[0][r] += comb[rbase + r][n0];
        acc0[1][r] += comb[rbase + r][n0 + 16];
        acc0[2][r] += comb[rbase + r][n0 + 32];
        acc0[3][r] += comb[rbase + r][n0 + 48];
        acc1[0][r] += comb[16 + rbase + r][n0];
        acc1[1][r] += comb[16 + rbase + r][n0 + 16];
        acc1[2][r] += comb[16 + rbase + r][n0 + 32];
        acc1[3][r] += comb[16 + rbase + r][n0 + 48];
      }
    }
    __syncthreads();
  }

  if (kg == 0) {
    #pragma unroll
    for (int r = 0; r < 4; ++r) {
      int row0 = rbase + r;
      float s0 = scale_s[row0];
      size_t base0 = (size_t)(i0 + row0) * A;
      out[base0 + n0]      = acc0[0][r] * s0;
      out[base0 + n0 + 16] = acc0[1][r] * s0;
      out[base0 + n0 + 32] = acc0[2][r] * s0;
      out[base0 + n0 + 48] = acc0[3][r] * s0;
      int row1 = 16 + rbase + r;
      float s1 = scale_s[row1];
      size_t base1 = (size_t)(i0 + row1) * A;
      out[base1 + n0]      = acc1[0][r] * s1;
      out[base1 + n0 + 16] = acc1[1][r] * s1;
      out[base1 + n0 + 32] = acc1[2][r] * s1;
      out[base1 + n0 + 48] = acc1[3][r] * s1;
    }
  }
}

extern "C" void kernel_launch(void* const* d_in, const int* in_sizes, int n_in,
                              void* d_out, int out_size, void* d_ws, size_t ws_size,
                              hipStream_t stream) {
  // inputs: 0 batch[S,F] 1 xywh[S,4] 2 OW 3 OH 4 actor_weights[S] 5 avg_pos[S,2]
  //         6 W_h[F,2] 7 b_h[2] 8 W_g[F,A] 9 b_g[A] 10 num_person
  const float* batch = (const float*)d_in[0];
  const float* xywh  = (const float*)d_in[1];
  const float* W_h   = (const float*)d_in[6];
  const float* b_h   = (const float*)d_in[7];
  const float* W_g   = (const float*)d_in[8];
  const float* b_g   = (const float*)d_in[9];
  int S = in_sizes[4];
  int F = in_sizes[0] / S;
  int A = in_sizes[9];

  float* out    = (float*)d_out;
  float* out_tw = out;                        // [S,A]
  float* out_hp = out + (size_t)S * A;        // [S,2]

  // workspace: tgt2 bf16 [S/32][A][32], WgT bf16 [A][F], hx/hy/validf, cxy
  uint16_t* tgt2 = (uint16_t*)d_ws;
  uint16_t* WgT  = tgt2 + (size_t)A * S;
  float* hxv = (float*)(WgT + (size_t)A * F);
  float* hyv = hxv + S;
  float* vfv = hyv + S;
  float2* cxyv = (float2*)(vfv + S);

  k_head<<<dim3((S + 3) / 4), 256, 0, stream>>>(batch, xywh, W_h, b_h,
                                                out_hp, hxv, hyv, vfv, cxyv, S, F);
  k_prep_w<<<dim3((A * F / 8 + 255) / 256), 256, 0, stream>>>(W_g, WgT, F, A);
  k_targets_mfma<<<dim3(A / 128, S / 32), 256, 0, stream>>>(batch, WgT, b_g,
                                                            tgt2, S, F, A);
  k_gather_v17<<<dim3(S / 32), 1024, 0, stream>>>(tgt2, cxyv, hxv, hyv, vfv,
                                                  out_tw, S, A);
}